// Round 4
// baseline (46.702 us; speedup 1.0000x reference)
//
#include <hip/hip_runtime.h>

#define DECAY 0.9f
#define INHIB 0.1f
#define TH_DEC 0.9f
#define TH_INC 0.1f

// Fixed problem sizes
#define BATCH 32
#define SEQ   1024
#define IDIM  512
#define ODIM  512
#define SHEAD 32      // head covers s in [0,SHEAD); batches provably die at s~23
#define SDEPTH 4

// ws layout: proj [SEQ][BATCH][ODIM] fp32 (64 MB).
// After scan_head consumes rows s=0,1 they are reused as a state stash:
//   proj[0][b][o] = saved mem   (only if batch alive at s=SHEAD)
//   proj[1][b][o] = saved thr;  proj[1][b][0] < 0 marks "batch dead, output done"
//   (thr is provably always > 0 and never NaN, so -1.0f is unambiguous)

// ---------------- DPP wave64 sum (VALU-only) ----------------
template <int CTRL>
__device__ __forceinline__ float dpp_add(float x) {
    int v = __builtin_amdgcn_update_dpp(0, __float_as_int(x), CTRL, 0xf, 0xf, true);
    return x + __int_as_float(v);
}
__device__ __forceinline__ float wave_sum_bcast(float x) {
    x = dpp_add<0x111>(x);   // row_shr:1
    x = dpp_add<0x112>(x);   // row_shr:2
    x = dpp_add<0x114>(x);   // row_shr:4
    x = dpp_add<0x118>(x);   // row_shr:8
    x = dpp_add<0x142>(x);   // row_bcast:15
    x = dpp_add<0x143>(x);   // row_bcast:31 -> lane 63 holds wave total
    return __int_as_float(__builtin_amdgcn_readlane(__float_as_int(x), 63));
}

// ================= GEMM head + full-output pre-zero =================
// grid (BATCH, ODIM/64), 128 threads. Tile 32(s) x 64(o), BK=32, microtile 4x4.
// Also zeroes the ENTIRE 64MB output via paced stores (VMEM overlaps LDS/VALU).
__global__ __launch_bounds__(128) void gemm_head(
    const float* __restrict__ X, const float* __restrict__ Wm,
    const float* __restrict__ bias, float* __restrict__ P,
    float* __restrict__ Out)
{
    __shared__ float As[32][32];
    __shared__ float Bs[32][64];

    const int b   = blockIdx.x;
    const int bn  = blockIdx.y * 64;
    const int tid = threadIdx.x;      // 0..127

    const int arow = tid >> 2, akq = (tid & 3) * 8;    // A: 8 floats/thread
    const int brow = tid >> 1, bkq = (tid & 1) * 16;   // B: 16 floats/thread
    const int tx = tid & 15, ty = tid >> 4;            // microtile 4(s) x 4(o)

    // zero-fill slab: 16384 float4 per block (256 KB), 128/thread, paced 8/k-tile
    const int blin = blockIdx.y * BATCH + blockIdx.x;  // 0..255
    float4* zp = (float4*)Out + (size_t)blin * 16384 + tid;
    const float4 zf4 = make_float4(0.f, 0.f, 0.f, 0.f);

    float acc[4][4];
#pragma unroll
    for (int i = 0; i < 4; ++i)
#pragma unroll
        for (int j = 0; j < 4; ++j) acc[i][j] = 0.0f;

    const float* aPtr = X  + ((size_t)b * SEQ + arow) * IDIM + akq;
    const float* bPtr = Wm + (size_t)(bn + brow) * IDIM + bkq;

    float4 a0 = *(const float4*)(aPtr);
    float4 a1 = *(const float4*)(aPtr + 4);
    float4 b0 = *(const float4*)(bPtr);
    float4 b1 = *(const float4*)(bPtr + 4);
    float4 b2 = *(const float4*)(bPtr + 8);
    float4 b3 = *(const float4*)(bPtr + 12);
    int zi = 0;

    for (int k0 = 0; k0 < IDIM; k0 += 32) {
        __syncthreads();   // previous inner loop done reading LDS
        As[akq+0][arow] = a0.x; As[akq+1][arow] = a0.y;
        As[akq+2][arow] = a0.z; As[akq+3][arow] = a0.w;
        As[akq+4][arow] = a1.x; As[akq+5][arow] = a1.y;
        As[akq+6][arow] = a1.z; As[akq+7][arow] = a1.w;
        Bs[bkq+ 0][brow] = b0.x; Bs[bkq+ 1][brow] = b0.y;
        Bs[bkq+ 2][brow] = b0.z; Bs[bkq+ 3][brow] = b0.w;
        Bs[bkq+ 4][brow] = b1.x; Bs[bkq+ 5][brow] = b1.y;
        Bs[bkq+ 6][brow] = b1.z; Bs[bkq+ 7][brow] = b1.w;
        Bs[bkq+ 8][brow] = b2.x; Bs[bkq+ 9][brow] = b2.y;
        Bs[bkq+10][brow] = b2.z; Bs[bkq+11][brow] = b2.w;
        Bs[bkq+12][brow] = b3.x; Bs[bkq+13][brow] = b3.y;
        Bs[bkq+14][brow] = b3.z; Bs[bkq+15][brow] = b3.w;

        if (k0 + 32 < IDIM) {             // register prefetch of next K-tile
            a0 = *(const float4*)(aPtr + k0 + 32);
            a1 = *(const float4*)(aPtr + k0 + 36);
            b0 = *(const float4*)(bPtr + k0 + 32);
            b1 = *(const float4*)(bPtr + k0 + 36);
            b2 = *(const float4*)(bPtr + k0 + 40);
            b3 = *(const float4*)(bPtr + k0 + 44);
        }
        // paced zero stores (8/iter x 16 iters = 128 = whole slab)
#pragma unroll
        for (int j = 0; j < 8; ++j) zp[(size_t)(zi + j) * 128] = zf4;
        zi += 8;
        __syncthreads();

#pragma unroll
        for (int kk = 0; kk < 32; ++kk) {
            float4 ar = *(const float4*)&As[kk][ty * 4];
            float4 br = *(const float4*)&Bs[kk][tx * 4];
            float a_[4] = {ar.x, ar.y, ar.z, ar.w};
            float b_[4] = {br.x, br.y, br.z, br.w};
#pragma unroll
            for (int i = 0; i < 4; ++i)
#pragma unroll
                for (int j = 0; j < 4; ++j)
                    acc[i][j] += a_[i] * b_[j];
        }
    }

    float4 bi = *(const float4*)&bias[bn + tx * 4];
#pragma unroll
    for (int i = 0; i < 4; ++i) {
        const int s = ty * 4 + i;
        float* dst = P + ((size_t)s * BATCH + b) * ODIM + bn + tx * 4;
        *(float4*)dst = make_float4(acc[i][0] + bi.x, acc[i][1] + bi.y,
                                    acc[i][2] + bi.z, acc[i][3] + bi.w);
    }
}

// ================= GEMM tail: proj[s][b][o], s in [SHEAD,SEQ) ===============
// grid (BATCH, ODIM/64), 128 threads, loops 31 s-tiles of 32. Correctness
// fallback only: early-outs when every batch is marked dead.
__global__ __launch_bounds__(128) void gemm_tail(
    const float* __restrict__ X, const float* __restrict__ Wm,
    const float* __restrict__ bias, float* __restrict__ P)
{
    {
        const int lane = threadIdx.x & 63;
        float v = -1.0f;
        if (lane < BATCH) v = P[(size_t)(BATCH + lane) * ODIM];  // thr stash / dead marker
        if (__ballot(v >= 0.0f) == 0ull) return;                 // nobody survived
    }

    __shared__ float As[32][32];
    __shared__ float Bs[32][64];

    const int b   = blockIdx.x;
    const int bn  = blockIdx.y * 64;
    const int tid = threadIdx.x;
    const int arow = tid >> 2, akq = (tid & 3) * 8;
    const int brow = tid >> 1, bkq = (tid & 1) * 16;
    const int tx = tid & 15, ty = tid >> 4;

    const float* bPtr = Wm + (size_t)(bn + brow) * IDIM + bkq;

    for (int st = 0; st < (SEQ - SHEAD) / 32; ++st) {
        const int s0 = SHEAD + st * 32;
        const float* aPtr = X + ((size_t)b * SEQ + s0 + arow) * IDIM + akq;

        float acc[4][4];
#pragma unroll
        for (int i = 0; i < 4; ++i)
#pragma unroll
            for (int j = 0; j < 4; ++j) acc[i][j] = 0.0f;

        for (int k0 = 0; k0 < IDIM; k0 += 32) {
            float4 a0 = *(const float4*)(aPtr + k0);
            float4 a1 = *(const float4*)(aPtr + k0 + 4);
            float4 b0 = *(const float4*)(bPtr + k0);
            float4 b1 = *(const float4*)(bPtr + k0 + 4);
            float4 b2 = *(const float4*)(bPtr + k0 + 8);
            float4 b3 = *(const float4*)(bPtr + k0 + 12);
            __syncthreads();
            As[akq+0][arow] = a0.x; As[akq+1][arow] = a0.y;
            As[akq+2][arow] = a0.z; As[akq+3][arow] = a0.w;
            As[akq+4][arow] = a1.x; As[akq+5][arow] = a1.y;
            As[akq+6][arow] = a1.z; As[akq+7][arow] = a1.w;
            Bs[bkq+ 0][brow] = b0.x; Bs[bkq+ 1][brow] = b0.y;
            Bs[bkq+ 2][brow] = b0.z; Bs[bkq+ 3][brow] = b0.w;
            Bs[bkq+ 4][brow] = b1.x; Bs[bkq+ 5][brow] = b1.y;
            Bs[bkq+ 6][brow] = b1.z; Bs[bkq+ 7][brow] = b1.w;
            Bs[bkq+ 8][brow] = b2.x; Bs[bkq+ 9][brow] = b2.y;
            Bs[bkq+10][brow] = b2.z; Bs[bkq+11][brow] = b2.w;
            Bs[bkq+12][brow] = b3.x; Bs[bkq+13][brow] = b3.y;
            Bs[bkq+14][brow] = b3.z; Bs[bkq+15][brow] = b3.w;
            __syncthreads();
#pragma unroll
            for (int kk = 0; kk < 32; ++kk) {
                float4 ar = *(const float4*)&As[kk][ty * 4];
                float4 br = *(const float4*)&Bs[kk][tx * 4];
                float a_[4] = {ar.x, ar.y, ar.z, ar.w};
                float b_[4] = {br.x, br.y, br.z, br.w};
#pragma unroll
                for (int i = 0; i < 4; ++i)
#pragma unroll
                    for (int j = 0; j < 4; ++j)
                        acc[i][j] += a_[i] * b_[j];
            }
        }

        float4 bi = *(const float4*)&bias[bn + tx * 4];
#pragma unroll
        for (int i = 0; i < 4; ++i) {
            const int s = s0 + ty * 4 + i;
            float* dst = P + ((size_t)s * BATCH + b) * ODIM + bn + tx * 4;
            *(float4*)dst = make_float4(acc[i][0] + bi.x, acc[i][1] + bi.y,
                                        acc[i][2] + bi.z, acc[i][3] + bi.w);
        }
    }
}

// ================= Scan =================
// NOTE: the membrane reset MUST remain the literal expression
//   mem = mem*(1-spike) + spike*(mem-thr)
// to reproduce IEEE inf*0=NaN semantics of the reference (produces NaN after
// the +-inf step; NaN sum is then an absorbing all-zero-spikes state).
#define UPD(m, t, pv, sp) {                         \
        float cur = (pv) - shift;                   \
        (m) = DECAY * (m) + cur;                    \
        float spike = ((m) >= (t)) ? 1.0f : 0.0f;   \
        (m) = (m) * (1.0f - spike) + spike * ((m) - (t)); \
        (t) = TH_DEC * (t) + TH_INC * spike;        \
        (sp) = spike; }

__global__ __launch_bounds__(64) void scan_head(float* P, float* __restrict__ Out)
{
    const int b    = blockIdx.x;
    const int lane = threadIdx.x;
    const size_t rowStride = (size_t)BATCH * ODIM;

    const float* p0 = P + (size_t)b * ODIM + lane * 4;
    const float* p1 = p0 + 256;
    float* o0 = Out + (size_t)b * SEQ * ODIM + lane * 4;
    float* o1 = o0 + 256;

    float4 mem0 = make_float4(0.f, 0.f, 0.f, 0.f);
    float4 mem1 = make_float4(0.f, 0.f, 0.f, 0.f);
    float4 thr0 = make_float4(1.f, 1.f, 1.f, 1.f);
    float4 thr1 = make_float4(1.f, 1.f, 1.f, 1.f);

    float4 buf0[SDEPTH], buf1[SDEPTH];
#pragma unroll
    for (int u = 0; u < SDEPTH; ++u) {
        buf0[u] = *(const float4*)(p0 + (size_t)u * rowStride);
        buf1[u] = *(const float4*)(p1 + (size_t)u * rowStride);
    }

    for (int so = 0; so < SHEAD; so += SDEPTH) {
#pragma unroll
        for (int u = 0; u < SDEPTH; ++u) {
            const int s = so + u;
            const float4 pa = buf0[u];
            const float4 pb = buf1[u];
            const int sn = s + SDEPTH;
            if (sn < SHEAD) {
                buf0[u] = *(const float4*)(p0 + (size_t)sn * rowStride);
                buf1[u] = *(const float4*)(p1 + (size_t)sn * rowStride);
            }

            float part = ((mem0.x + mem0.y) + (mem0.z + mem0.w))
                       + ((mem1.x + mem1.y) + (mem1.z + mem1.w));
            const float tot = wave_sum_bcast(part);

            if (tot != tot) {   // NaN: absorbing; tail already pre-zeroed by gemm_head
                if (lane == 0) P[(size_t)(BATCH + b) * ODIM] = -1.0f;   // dead marker
                return;
            }

            const float shift = INHIB * tot;
            float4 sp0, sp1;
            UPD(mem0.x, thr0.x, pa.x, sp0.x);
            UPD(mem0.y, thr0.y, pa.y, sp0.y);
            UPD(mem0.z, thr0.z, pa.z, sp0.z);
            UPD(mem0.w, thr0.w, pa.w, sp0.w);
            UPD(mem1.x, thr1.x, pb.x, sp1.x);
            UPD(mem1.y, thr1.y, pb.y, sp1.y);
            UPD(mem1.z, thr1.z, pb.z, sp1.z);
            UPD(mem1.w, thr1.w, pb.w, sp1.w);

            *(float4*)(o0 + (size_t)s * ODIM) = sp0;
            *(float4*)(o1 + (size_t)s * ODIM) = sp1;
        }
    }

    // alive at s=SHEAD: stash state into consumed proj rows 0 (mem) and 1 (thr)
    float* sm = P + (size_t)b * ODIM;
    float* st = P + (size_t)(BATCH + b) * ODIM;
    *(float4*)(sm + lane * 4)       = mem0;
    *(float4*)(sm + 256 + lane * 4) = mem1;
    *(float4*)(st + lane * 4)       = thr0;   // thr > 0 always => marks "alive"
    *(float4*)(st + 256 + lane * 4) = thr1;
}

__global__ __launch_bounds__(64) void scan_tail(float* P, float* __restrict__ Out)
{
    const int b    = blockIdx.x;
    const int lane = threadIdx.x;

    if (P[(size_t)(BATCH + b) * ODIM] < 0.0f) return;   // dead: output already complete

    const size_t rowStride = (size_t)BATCH * ODIM;
    const float* p0 = P + (size_t)b * ODIM + lane * 4;
    const float* p1 = p0 + 256;
    float* o0 = Out + (size_t)b * SEQ * ODIM + lane * 4;
    float* o1 = o0 + 256;

    const float* sm = P + (size_t)b * ODIM;
    const float* st = P + (size_t)(BATCH + b) * ODIM;
    float4 mem0 = *(const float4*)(sm + lane * 4);
    float4 mem1 = *(const float4*)(sm + 256 + lane * 4);
    float4 thr0 = *(const float4*)(st + lane * 4);
    float4 thr1 = *(const float4*)(st + 256 + lane * 4);

    float4 buf0[SDEPTH], buf1[SDEPTH];
#pragma unroll
    for (int u = 0; u < SDEPTH; ++u) {
        buf0[u] = *(const float4*)(p0 + (size_t)(SHEAD + u) * rowStride);
        buf1[u] = *(const float4*)(p1 + (size_t)(SHEAD + u) * rowStride);
    }

    for (int so = SHEAD; so < SEQ; so += SDEPTH) {
#pragma unroll
        for (int u = 0; u < SDEPTH; ++u) {
            const int s = so + u;
            const float4 pa = buf0[u];
            const float4 pb = buf1[u];
            const int sn = s + SDEPTH;
            if (sn < SEQ) {
                buf0[u] = *(const float4*)(p0 + (size_t)sn * rowStride);
                buf1[u] = *(const float4*)(p1 + (size_t)sn * rowStride);
            }

            float part = ((mem0.x + mem0.y) + (mem0.z + mem0.w))
                       + ((mem1.x + mem1.y) + (mem1.z + mem1.w));
            const float tot = wave_sum_bcast(part);

            if (tot != tot) return;   // tail already pre-zeroed

            const float shift = INHIB * tot;
            float4 sp0, sp1;
            UPD(mem0.x, thr0.x, pa.x, sp0.x);
            UPD(mem0.y, thr0.y, pa.y, sp0.y);
            UPD(mem0.z, thr0.z, pa.z, sp0.z);
            UPD(mem0.w, thr0.w, pa.w, sp0.w);
            UPD(mem1.x, thr1.x, pb.x, sp1.x);
            UPD(mem1.y, thr1.y, pb.y, sp1.y);
            UPD(mem1.z, thr1.z, pb.z, sp1.z);
            UPD(mem1.w, thr1.w, pb.w, sp1.w);

            *(float4*)(o0 + (size_t)s * ODIM) = sp0;
            *(float4*)(o1 + (size_t)s * ODIM) = sp1;
        }
    }
}
#undef UPD

extern "C" void kernel_launch(void* const* d_in, const int* in_sizes, int n_in,
                              void* d_out, int out_size, void* d_ws, size_t ws_size,
                              hipStream_t stream) {
    const float* x    = (const float*)d_in[0];   // [B, S, I]
    const float* W    = (const float*)d_in[1];   // [O, I]
    const float* bias = (const float*)d_in[2];   // [O]
    float* out  = (float*)d_out;                 // [B, S, O]
    float* proj = (float*)d_ws;                  // [S, B, O] scratch (64 MB)

    gemm_head<<<dim3(BATCH, ODIM / 64), dim3(128), 0, stream>>>(x, W, bias, proj, out);
    scan_head<<<dim3(BATCH), dim3(64), 0, stream>>>(proj, out);
    gemm_tail<<<dim3(BATCH, ODIM / 64), dim3(128), 0, stream>>>(x, W, bias, proj);
    scan_tail<<<dim3(BATCH), dim3(64), 0, stream>>>(proj, out);
}

// Round 5
// 38.849 us; speedup vs baseline: 1.2022x; 1.2022x over previous
//
#include <hip/hip_runtime.h>

#define DECAY 0.9f
#define INHIB 0.1f
#define TH_DEC 0.9f
#define TH_INC 0.1f

// Fixed problem sizes
#define BATCH 32
#define SEQ   1024
#define IDIM  512
#define ODIM  512
#define SHEAD 32      // head covers s in [0,SHEAD); batches provably die at s~23
#define SDEPTH 4

// ws layout: proj [SEQ][BATCH][ODIM] fp32 (64 MB).
// After scan_head consumes rows s=0,1 they are reused as a state stash:
//   proj[0][b][o] = saved mem   (only if batch alive at s=SHEAD)
//   proj[1][b][o] = saved thr;  proj[1][b][0] < 0 marks "batch dead, output done"
//   (thr is provably always > 0 and never NaN, so -1.0f is unambiguous)

// ---------------- DPP wave64 sum (VALU-only) ----------------
template <int CTRL>
__device__ __forceinline__ float dpp_add(float x) {
    int v = __builtin_amdgcn_update_dpp(0, __float_as_int(x), CTRL, 0xf, 0xf, true);
    return x + __int_as_float(v);
}
__device__ __forceinline__ float wave_sum_bcast(float x) {
    x = dpp_add<0x111>(x);   // row_shr:1
    x = dpp_add<0x112>(x);   // row_shr:2
    x = dpp_add<0x114>(x);   // row_shr:4
    x = dpp_add<0x118>(x);   // row_shr:8
    x = dpp_add<0x142>(x);   // row_bcast:15
    x = dpp_add<0x143>(x);   // row_bcast:31 -> lane 63 holds wave total
    return __int_as_float(__builtin_amdgcn_readlane(__float_as_int(x), 63));
}

// ================= Fused head: GEMM blocks + dedicated fill blocks =========
// grid 512 x 128 threads.
//   blocks [0,256): GEMM proj[s][b][o], s<SHEAD. Tile 32(s)x64(o), BK=32, micro 4x4.
//   blocks [256,512): zero-fill Out region s in [SHEAD,SEQ) (62 MB), pure store
//     loops on the VMEM pipe -> overlaps the GEMM's LDS/VALU work on co-resident CUs.
__global__ __launch_bounds__(128) void head_fused(
    const float* __restrict__ X, const float* __restrict__ Wm,
    const float* __restrict__ bias, float* __restrict__ P,
    float* __restrict__ Out)
{
    __shared__ float As[32][32];
    __shared__ float Bs[32][64];

    const int tid = threadIdx.x;      // 0..127

    if (blockIdx.x >= 256) {
        // ---- fill block: zero Out[b][SHEAD..SEQ)[*], chunked ----
        const int blk_f = blockIdx.x - 256;          // 0..255
        const int b     = blk_f >> 3;                // 8 chunks per batch
        const int chunk = blk_f & 7;
        // per-batch region: 126976 float4 starting at row SHEAD; 8 x 15872
        float4* base = (float4*)Out + (size_t)b * (SEQ * ODIM / 4)
                     + (SHEAD * ODIM / 4) + (size_t)chunk * 15872;
        const float4 z = make_float4(0.f, 0.f, 0.f, 0.f);
        for (int j = tid; j < 15872; j += 128) base[j] = z;
        return;
    }

    // ---- GEMM block ----
    const int b  = blockIdx.x & 31;
    const int bn = (blockIdx.x >> 5) * 64;

    const int arow = tid >> 2, akq = (tid & 3) * 8;    // A: 8 floats/thread
    const int brow = tid >> 1, bkq = (tid & 1) * 16;   // B: 16 floats/thread
    const int tx = tid & 15, ty = tid >> 4;            // microtile 4(s) x 4(o)

    float acc[4][4];
#pragma unroll
    for (int i = 0; i < 4; ++i)
#pragma unroll
        for (int j = 0; j < 4; ++j) acc[i][j] = 0.0f;

    const float* aPtr = X  + ((size_t)b * SEQ + arow) * IDIM + akq;
    const float* bPtr = Wm + (size_t)(bn + brow) * IDIM + bkq;

    float4 a0 = *(const float4*)(aPtr);
    float4 a1 = *(const float4*)(aPtr + 4);
    float4 b0 = *(const float4*)(bPtr);
    float4 b1 = *(const float4*)(bPtr + 4);
    float4 b2 = *(const float4*)(bPtr + 8);
    float4 b3 = *(const float4*)(bPtr + 12);

    for (int k0 = 0; k0 < IDIM; k0 += 32) {
        __syncthreads();   // previous inner loop done reading LDS
        As[akq+0][arow] = a0.x; As[akq+1][arow] = a0.y;
        As[akq+2][arow] = a0.z; As[akq+3][arow] = a0.w;
        As[akq+4][arow] = a1.x; As[akq+5][arow] = a1.y;
        As[akq+6][arow] = a1.z; As[akq+7][arow] = a1.w;
        Bs[bkq+ 0][brow] = b0.x; Bs[bkq+ 1][brow] = b0.y;
        Bs[bkq+ 2][brow] = b0.z; Bs[bkq+ 3][brow] = b0.w;
        Bs[bkq+ 4][brow] = b1.x; Bs[bkq+ 5][brow] = b1.y;
        Bs[bkq+ 6][brow] = b1.z; Bs[bkq+ 7][brow] = b1.w;
        Bs[bkq+ 8][brow] = b2.x; Bs[bkq+ 9][brow] = b2.y;
        Bs[bkq+10][brow] = b2.z; Bs[bkq+11][brow] = b2.w;
        Bs[bkq+12][brow] = b3.x; Bs[bkq+13][brow] = b3.y;
        Bs[bkq+14][brow] = b3.z; Bs[bkq+15][brow] = b3.w;

        if (k0 + 32 < IDIM) {             // register prefetch of next K-tile
            a0 = *(const float4*)(aPtr + k0 + 32);
            a1 = *(const float4*)(aPtr + k0 + 36);
            b0 = *(const float4*)(bPtr + k0 + 32);
            b1 = *(const float4*)(bPtr + k0 + 36);
            b2 = *(const float4*)(bPtr + k0 + 40);
            b3 = *(const float4*)(bPtr + k0 + 44);
        }
        __syncthreads();

#pragma unroll
        for (int kk = 0; kk < 32; ++kk) {
            float4 ar = *(const float4*)&As[kk][ty * 4];
            float4 br = *(const float4*)&Bs[kk][tx * 4];
            float a_[4] = {ar.x, ar.y, ar.z, ar.w};
            float b_[4] = {br.x, br.y, br.z, br.w};
#pragma unroll
            for (int i = 0; i < 4; ++i)
#pragma unroll
                for (int j = 0; j < 4; ++j)
                    acc[i][j] += a_[i] * b_[j];
        }
    }

    float4 bi = *(const float4*)&bias[bn + tx * 4];
#pragma unroll
    for (int i = 0; i < 4; ++i) {
        const int s = ty * 4 + i;
        float* dst = P + ((size_t)s * BATCH + b) * ODIM + bn + tx * 4;
        *(float4*)dst = make_float4(acc[i][0] + bi.x, acc[i][1] + bi.y,
                                    acc[i][2] + bi.z, acc[i][3] + bi.w);
    }
}

// ================= GEMM tail: proj[s][b][o], s in [SHEAD,SEQ) ===============
// grid (BATCH, ODIM/64), 128 threads, loops 31 s-tiles of 32. Correctness
// fallback only: early-outs when every batch is marked dead.
__global__ __launch_bounds__(128) void gemm_tail(
    const float* __restrict__ X, const float* __restrict__ Wm,
    const float* __restrict__ bias, float* __restrict__ P)
{
    {
        const int lane = threadIdx.x & 63;
        float v = -1.0f;
        if (lane < BATCH) v = P[(size_t)(BATCH + lane) * ODIM];  // thr stash / dead marker
        if (__ballot(v >= 0.0f) == 0ull) return;                 // nobody survived
    }

    __shared__ float As[32][32];
    __shared__ float Bs[32][64];

    const int b   = blockIdx.x;
    const int bn  = blockIdx.y * 64;
    const int tid = threadIdx.x;
    const int arow = tid >> 2, akq = (tid & 3) * 8;
    const int brow = tid >> 1, bkq = (tid & 1) * 16;
    const int tx = tid & 15, ty = tid >> 4;

    const float* bPtr = Wm + (size_t)(bn + brow) * IDIM + bkq;

    for (int st = 0; st < (SEQ - SHEAD) / 32; ++st) {
        const int s0 = SHEAD + st * 32;
        const float* aPtr = X + ((size_t)b * SEQ + s0 + arow) * IDIM + akq;

        float acc[4][4];
#pragma unroll
        for (int i = 0; i < 4; ++i)
#pragma unroll
            for (int j = 0; j < 4; ++j) acc[i][j] = 0.0f;

        for (int k0 = 0; k0 < IDIM; k0 += 32) {
            float4 a0 = *(const float4*)(aPtr + k0);
            float4 a1 = *(const float4*)(aPtr + k0 + 4);
            float4 b0 = *(const float4*)(bPtr + k0);
            float4 b1 = *(const float4*)(bPtr + k0 + 4);
            float4 b2 = *(const float4*)(bPtr + k0 + 8);
            float4 b3 = *(const float4*)(bPtr + k0 + 12);
            __syncthreads();
            As[akq+0][arow] = a0.x; As[akq+1][arow] = a0.y;
            As[akq+2][arow] = a0.z; As[akq+3][arow] = a0.w;
            As[akq+4][arow] = a1.x; As[akq+5][arow] = a1.y;
            As[akq+6][arow] = a1.z; As[akq+7][arow] = a1.w;
            Bs[bkq+ 0][brow] = b0.x; Bs[bkq+ 1][brow] = b0.y;
            Bs[bkq+ 2][brow] = b0.z; Bs[bkq+ 3][brow] = b0.w;
            Bs[bkq+ 4][brow] = b1.x; Bs[bkq+ 5][brow] = b1.y;
            Bs[bkq+ 6][brow] = b1.z; Bs[bkq+ 7][brow] = b1.w;
            Bs[bkq+ 8][brow] = b2.x; Bs[bkq+ 9][brow] = b2.y;
            Bs[bkq+10][brow] = b2.z; Bs[bkq+11][brow] = b2.w;
            Bs[bkq+12][brow] = b3.x; Bs[bkq+13][brow] = b3.y;
            Bs[bkq+14][brow] = b3.z; Bs[bkq+15][brow] = b3.w;
            __syncthreads();
#pragma unroll
            for (int kk = 0; kk < 32; ++kk) {
                float4 ar = *(const float4*)&As[kk][ty * 4];
                float4 br = *(const float4*)&Bs[kk][tx * 4];
                float a_[4] = {ar.x, ar.y, ar.z, ar.w};
                float b_[4] = {br.x, br.y, br.z, br.w};
#pragma unroll
                for (int i = 0; i < 4; ++i)
#pragma unroll
                    for (int j = 0; j < 4; ++j)
                        acc[i][j] += a_[i] * b_[j];
            }
        }

        float4 bi = *(const float4*)&bias[bn + tx * 4];
#pragma unroll
        for (int i = 0; i < 4; ++i) {
            const int s = s0 + ty * 4 + i;
            float* dst = P + ((size_t)s * BATCH + b) * ODIM + bn + tx * 4;
            *(float4*)dst = make_float4(acc[i][0] + bi.x, acc[i][1] + bi.y,
                                        acc[i][2] + bi.z, acc[i][3] + bi.w);
        }
    }
}

// ================= Scan =================
// NOTE: the membrane reset MUST remain the literal expression
//   mem = mem*(1-spike) + spike*(mem-thr)
// to reproduce IEEE inf*0=NaN semantics of the reference (produces NaN after
// the +-inf step; NaN sum is then an absorbing all-zero-spikes state).
#define UPD(m, t, pv, sp) {                         \
        float cur = (pv) - shift;                   \
        (m) = DECAY * (m) + cur;                    \
        float spike = ((m) >= (t)) ? 1.0f : 0.0f;   \
        (m) = (m) * (1.0f - spike) + spike * ((m) - (t)); \
        (t) = TH_DEC * (t) + TH_INC * spike;        \
        (sp) = spike; }

__global__ __launch_bounds__(64) void scan_head(float* P, float* __restrict__ Out)
{
    const int b    = blockIdx.x;
    const int lane = threadIdx.x;
    const size_t rowStride = (size_t)BATCH * ODIM;

    const float* p0 = P + (size_t)b * ODIM + lane * 4;
    const float* p1 = p0 + 256;
    float* o0 = Out + (size_t)b * SEQ * ODIM + lane * 4;
    float* o1 = o0 + 256;

    float4 mem0 = make_float4(0.f, 0.f, 0.f, 0.f);
    float4 mem1 = make_float4(0.f, 0.f, 0.f, 0.f);
    float4 thr0 = make_float4(1.f, 1.f, 1.f, 1.f);
    float4 thr1 = make_float4(1.f, 1.f, 1.f, 1.f);

    float4 buf0[SDEPTH], buf1[SDEPTH];
#pragma unroll
    for (int u = 0; u < SDEPTH; ++u) {
        buf0[u] = *(const float4*)(p0 + (size_t)u * rowStride);
        buf1[u] = *(const float4*)(p1 + (size_t)u * rowStride);
    }

    for (int so = 0; so < SHEAD; so += SDEPTH) {
#pragma unroll
        for (int u = 0; u < SDEPTH; ++u) {
            const int s = so + u;
            const float4 pa = buf0[u];
            const float4 pb = buf1[u];
            const int sn = s + SDEPTH;
            if (sn < SHEAD) {
                buf0[u] = *(const float4*)(p0 + (size_t)sn * rowStride);
                buf1[u] = *(const float4*)(p1 + (size_t)sn * rowStride);
            }

            float part = ((mem0.x + mem0.y) + (mem0.z + mem0.w))
                       + ((mem1.x + mem1.y) + (mem1.z + mem1.w));
            const float tot = wave_sum_bcast(part);

            if (tot != tot) {   // NaN: absorbing. Zero [s,SHEAD); s>=SHEAD pre-zeroed.
                const float4 z = make_float4(0.f, 0.f, 0.f, 0.f);
                for (int r = s; r < SHEAD; ++r) {
                    *(float4*)(o0 + (size_t)r * ODIM) = z;
                    *(float4*)(o1 + (size_t)r * ODIM) = z;
                }
                if (lane == 0) P[(size_t)(BATCH + b) * ODIM] = -1.0f;   // dead marker
                return;
            }

            const float shift = INHIB * tot;
            float4 sp0, sp1;
            UPD(mem0.x, thr0.x, pa.x, sp0.x);
            UPD(mem0.y, thr0.y, pa.y, sp0.y);
            UPD(mem0.z, thr0.z, pa.z, sp0.z);
            UPD(mem0.w, thr0.w, pa.w, sp0.w);
            UPD(mem1.x, thr1.x, pb.x, sp1.x);
            UPD(mem1.y, thr1.y, pb.y, sp1.y);
            UPD(mem1.z, thr1.z, pb.z, sp1.z);
            UPD(mem1.w, thr1.w, pb.w, sp1.w);

            *(float4*)(o0 + (size_t)s * ODIM) = sp0;
            *(float4*)(o1 + (size_t)s * ODIM) = sp1;
        }
    }

    // alive at s=SHEAD: stash state into consumed proj rows 0 (mem) and 1 (thr)
    float* sm = P + (size_t)b * ODIM;
    float* st = P + (size_t)(BATCH + b) * ODIM;
    *(float4*)(sm + lane * 4)       = mem0;
    *(float4*)(sm + 256 + lane * 4) = mem1;
    *(float4*)(st + lane * 4)       = thr0;   // thr > 0 always => marks "alive"
    *(float4*)(st + 256 + lane * 4) = thr1;
}

__global__ __launch_bounds__(64) void scan_tail(float* P, float* __restrict__ Out)
{
    const int b    = blockIdx.x;
    const int lane = threadIdx.x;

    if (P[(size_t)(BATCH + b) * ODIM] < 0.0f) return;   // dead: output already complete

    const size_t rowStride = (size_t)BATCH * ODIM;
    const float* p0 = P + (size_t)b * ODIM + lane * 4;
    const float* p1 = p0 + 256;
    float* o0 = Out + (size_t)b * SEQ * ODIM + lane * 4;
    float* o1 = o0 + 256;

    const float* sm = P + (size_t)b * ODIM;
    const float* st = P + (size_t)(BATCH + b) * ODIM;
    float4 mem0 = *(const float4*)(sm + lane * 4);
    float4 mem1 = *(const float4*)(sm + 256 + lane * 4);
    float4 thr0 = *(const float4*)(st + lane * 4);
    float4 thr1 = *(const float4*)(st + 256 + lane * 4);

    float4 buf0[SDEPTH], buf1[SDEPTH];
#pragma unroll
    for (int u = 0; u < SDEPTH; ++u) {
        buf0[u] = *(const float4*)(p0 + (size_t)(SHEAD + u) * rowStride);
        buf1[u] = *(const float4*)(p1 + (size_t)(SHEAD + u) * rowStride);
    }

    for (int so = SHEAD; so < SEQ; so += SDEPTH) {
#pragma unroll
        for (int u = 0; u < SDEPTH; ++u) {
            const int s = so + u;
            const float4 pa = buf0[u];
            const float4 pb = buf1[u];
            const int sn = s + SDEPTH;
            if (sn < SEQ) {
                buf0[u] = *(const float4*)(p0 + (size_t)sn * rowStride);
                buf1[u] = *(const float4*)(p1 + (size_t)sn * rowStride);
            }

            float part = ((mem0.x + mem0.y) + (mem0.z + mem0.w))
                       + ((mem1.x + mem1.y) + (mem1.z + mem1.w));
            const float tot = wave_sum_bcast(part);

            if (tot != tot) return;   // tail already pre-zeroed by head_fused

            const float shift = INHIB * tot;
            float4 sp0, sp1;
            UPD(mem0.x, thr0.x, pa.x, sp0.x);
            UPD(mem0.y, thr0.y, pa.y, sp0.y);
            UPD(mem0.z, thr0.z, pa.z, sp0.z);
            UPD(mem0.w, thr0.w, pa.w, sp0.w);
            UPD(mem1.x, thr1.x, pb.x, sp1.x);
            UPD(mem1.y, thr1.y, pb.y, sp1.y);
            UPD(mem1.z, thr1.z, pb.z, sp1.z);
            UPD(mem1.w, thr1.w, pb.w, sp1.w);

            *(float4*)(o0 + (size_t)s * ODIM) = sp0;
            *(float4*)(o1 + (size_t)s * ODIM) = sp1;
        }
    }
}
#undef UPD

extern "C" void kernel_launch(void* const* d_in, const int* in_sizes, int n_in,
                              void* d_out, int out_size, void* d_ws, size_t ws_size,
                              hipStream_t stream) {
    const float* x    = (const float*)d_in[0];   // [B, S, I]
    const float* W    = (const float*)d_in[1];   // [O, I]
    const float* bias = (const float*)d_in[2];   // [O]
    float* out  = (float*)d_out;                 // [B, S, O]
    float* proj = (float*)d_ws;                  // [S, B, O] scratch (64 MB)

    head_fused<<<dim3(512), dim3(128), 0, stream>>>(x, W, bias, proj, out);
    scan_head<<<dim3(BATCH), dim3(64), 0, stream>>>(proj, out);
    gemm_tail<<<dim3(BATCH, ODIM / 64), dim3(128), 0, stream>>>(x, W, bias, proj);
    scan_tail<<<dim3(BATCH), dim3(64), 0, stream>>>(proj, out);
}